// Round 5
// baseline (1199.723 us; speedup 1.0000x reference)
//
#include <hip/hip_runtime.h>

#define BB 16
#define NN 4096
#define SS 1024
#define KNB 32

// ---- ws layout (in 4-byte words) ----
#define FPSIDX_OFF 0                         // int[BB*SS]
#define GIDX_OFF   (BB*SS)                   // int[BB*SS*KNB]
#define NORM_OFF   (GIDX_OFF + BB*SS*KNB)    // float[BB*NN]
#define FPIN_OFF   (NORM_OFF + BB*NN)        // float[BB*SS*9]
#define WF_OFF     (FPIN_OFF + BB*SS*9)      // float[13120]

// folded-weight layout (floats, within wf)
#define W0T 0          // [9][64]
#define B0F 576
#define W1T 640        // [64][64]
#define B1F 4736
#define W2T 4800       // [64][128]
#define B2F 12992

typedef float v2f __attribute__((ext_vector_type(2)));

// ---- K1: fold BN into weights, transpose to [c][f] ----
__global__ __launch_bounds__(128) void k_fold(
    const float* W0,const float* b0,const float* g0,const float* be0,const float* m0,const float* v0,
    const float* W1,const float* b1,const float* g1,const float* be1,const float* m1,const float* v1,
    const float* W2,const float* b2,const float* g2,const float* be2,const float* m2,const float* v2,
    float* wf){
  int t = threadIdx.x;
  if (t < 64){
    float s = g0[t]/sqrtf(v0[t]+1e-5f);
    wf[B0F+t] = (b0[t]-m0[t])*s + be0[t];
    for (int c=0;c<9;c++) wf[W0T + c*64 + t] = W0[t*9+c]*s;
    float s1 = g1[t]/sqrtf(v1[t]+1e-5f);
    wf[B1F+t] = (b1[t]-m1[t])*s1 + be1[t];
    for (int c=0;c<64;c++) wf[W1T + c*64 + t] = W1[t*64+c]*s1;
  }
  if (t < 128){
    float s2 = g2[t]/sqrtf(v2[t]+1e-5f);
    wf[B2F+t] = (b2[t]-m2[t])*s2 + be2[t];
    for (int c=0;c<64;c++) wf[W2T + c*128 + t] = W2[t*64+c]*s2;
  }
}

// ---- K2: per-point squared norms (exact ref order, no FMA) ----
__global__ __launch_bounds__(256) void k_norm(const float* xyz, float* nrm){
  int i = blockIdx.x*256 + threadIdx.x;     // < BB*NN
  int b = i >> 12, n = i & (NN-1);
  const float* X = xyz + (size_t)b*3*NN;
  float x=X[n], y=X[NN+n], z=X[2*NN+n];
  nrm[i] = __fadd_rn(__fadd_rn(__fmul_rn(x,x),__fmul_rn(y,y)),__fmul_rn(z,z));
}

// ---- K3: farthest point sampling ----
// 512 thr (8 waves, 2/SIMD for TLP), 8 pts/thread processed as float2 pairs
// (contract(off): plain mul/add == __fmul_rn/__fadd_rn, packable to v_pk).
// Wave argmax via DPP u64-key max-reduce (identical to proven r4 version);
// cross-wave: 8 slots, 3-level u64 max tree; centroid via one b128 read.
template<int CTRL, int RMASK>
__device__ __forceinline__ void dpp_max_step(unsigned &lo, unsigned &hi){
  unsigned nlo = (unsigned)__builtin_amdgcn_update_dpp(0, (int)lo, CTRL, RMASK, 0xF, false);
  unsigned nhi = (unsigned)__builtin_amdgcn_update_dpp(0, (int)hi, CTRL, RMASK, 0xF, false);
  unsigned long long cand = ((unsigned long long)nhi<<32) | nlo;
  unsigned long long curk = ((unsigned long long)hi<<32)  | lo;
  if (cand > curk){ lo = nlo; hi = nhi; }
}

__global__ __launch_bounds__(512) void k_fps(const float* xyz, int* fpsidx){
  #pragma clang fp contract(off)
  __shared__ float4 pxyz4[NN];
  __shared__ unsigned long long red[2][8];
  int b = blockIdx.x, tid = threadIdx.x;
  int w = tid >> 6, lane = tid & 63;
  const float* X = xyz + (size_t)b*3*NN;
  v2f lx[4], ly[4], lz[4], dist[4];
  #pragma unroll
  for (int m=0;m<4;m++){
    int p0 = tid + (2*m)*512, p1 = tid + (2*m+1)*512;
    float x0=X[p0], y0=X[NN+p0], z0=X[2*NN+p0];
    float x1=X[p1], y1=X[NN+p1], z1=X[2*NN+p1];
    float4 q0; q0.x=x0; q0.y=y0; q0.z=z0; q0.w=0.f;
    float4 q1; q1.x=x1; q1.y=y1; q1.z=z1; q1.w=0.f;
    pxyz4[p0] = q0; pxyz4[p1] = q1;
    lx[m].x=x0; lx[m].y=x1; ly[m].x=y0; ly[m].y=y1; lz[m].x=z0; lz[m].y=z1;
    dist[m].x=1e10f; dist[m].y=1e10f;
  }
  if (tid==0) fpsidx[b*SS] = 0;
  float cx = X[0], cy = X[NN], cz = X[2*NN];
  __syncthreads();
  for (int t=1;t<SS;t++){
    v2f cxx, cyy, czz;
    cxx.x=cx; cxx.y=cx; cyy.x=cy; cyy.y=cy; czz.x=cz; czz.y=cz;
    float bv = -1.0f; int bj = 0;
    #pragma unroll
    for (int m=0;m<4;m++){
      v2f dx = lx[m]-cxx, dy = ly[m]-cyy, dz = lz[m]-czz;
      v2f dd = (dx*dx + dy*dy) + dz*dz;
      v2f nd; nd.x = fminf(dist[m].x, dd.x); nd.y = fminf(dist[m].y, dd.y);
      dist[m] = nd;
      // pair-internal first-max (strict >: ties keep earlier element)
      bool pc = nd.y > nd.x;
      float vm = pc ? nd.y : nd.x;
      int   jm = pc ? (2*m+1) : (2*m);
      // vs running best (strict >: ties keep earlier pair)
      bool c = vm > bv;
      bv = c ? vm : bv;
      bj = c ? jm : bj;
    }
    int bi = tid + (bj << 9);                 // global point index (stride 512)
    unsigned lo = 0xFFFFFFFFu - (unsigned)bi; // ~idx: smaller idx -> bigger key
    unsigned hi = __float_as_uint(bv);        // dist>=0: bits monotone
    dpp_max_step<0x111,0xF>(lo,hi);   // row_shr:1
    dpp_max_step<0x112,0xF>(lo,hi);   // row_shr:2
    dpp_max_step<0x114,0xF>(lo,hi);   // row_shr:4
    dpp_max_step<0x118,0xF>(lo,hi);   // row_shr:8
    dpp_max_step<0x142,0xA>(lo,hi);   // row_bcast:15 -> rows 1,3
    dpp_max_step<0x143,0xC>(lo,hi);   // row_bcast:31 -> rows 2,3
    unsigned glo = (unsigned)__builtin_amdgcn_readlane((int)lo, 63);
    unsigned ghi = (unsigned)__builtin_amdgcn_readlane((int)hi, 63);
    if (lane==0) red[t&1][w] = ((unsigned long long)ghi<<32) | glo;
    __syncthreads();
    unsigned long long k0 = red[t&1][0], k1 = red[t&1][1];
    unsigned long long k2 = red[t&1][2], k3 = red[t&1][3];
    unsigned long long k4 = red[t&1][4], k5 = red[t&1][5];
    unsigned long long k6 = red[t&1][6], k7 = red[t&1][7];
    unsigned long long a0 = (k1>k0)?k1:k0;
    unsigned long long a1 = (k3>k2)?k3:k2;
    unsigned long long a2 = (k5>k4)?k5:k4;
    unsigned long long a3 = (k7>k6)?k7:k6;
    unsigned long long b0 = (a1>a0)?a1:a0;
    unsigned long long b1 = (a3>a2)?a3:a2;
    unsigned long long bk = (b1>b0)?b1:b0;
    int cur = (int)(0xFFFFFFFFu - (unsigned)(bk & 0xFFFFFFFFull));
    float4 cc = pxyz4[cur];
    cx = cc.x; cy = cc.y; cz = cc.z;
    if (tid==0) fpsidx[b*SS+t] = cur;
  }
}

// ---- K4: ball query (unchanged, known-correct) ----
__global__ __launch_bounds__(256) void k_ball(const float* xyz, const float* points, const float* nrm,
                                              const int* fpsidx, int* gidx, float* fpin, float* out0){
  int wid = threadIdx.x >> 6, lane = threadIdx.x & 63;
  int s = blockIdx.x*4 + wid;
  int b = s >> 10, si = s & (SS-1);
  const float* X = xyz + (size_t)b*3*NN;
  int cidx = fpsidx[s];
  float sx = X[cidx], sy = X[NN+cidx], sz = X[2*NN+cidx];
  float sn = nrm[b*NN + cidx];
  if (lane < 3){
    float v = lane==0?sx:(lane==1?sy:sz);
    fpin[s*9+lane] = v;
    out0[b*3*SS + lane*SS + si] = v;
  } else if (lane < 9){
    fpin[s*9+lane] = points[(size_t)b*6*NN + (size_t)(lane-3)*NN + cidx];
  }
  const float R2 = (float)(0.2*0.2);
  int total = 0; int first = 0;
  for (int ch=0; ch<NN/64; ch++){
    int n = ch*64 + lane;
    float pxv=X[n], pyv=X[NN+n], pzv=X[2*NN+n];
    float dot = __fmaf_rn(sz,pzv, __fmaf_rn(sy,pyv, __fmul_rn(sx,pxv)));
    float sqr = __fadd_rn(__fadd_rn(__fmul_rn(-2.0f,dot), sn), nrm[b*NN+n]);
    bool inc = (sqr <= R2);
    unsigned long long mask = __ballot(inc);
    if (total == 0 && mask != 0ull) first = ch*64 + (__ffsll((long long)mask) - 1);
    if (inc){
      int pos = total + __popcll(mask & ((1ull<<lane)-1ull));
      if (pos < KNB) gidx[s*KNB + pos] = n;
    }
    total += (int)__popcll(mask);
    if (total >= KNB) break;
  }
  if (total < KNB && lane >= total && lane < KNB) gidx[s*KNB + lane] = first;
}

// ---- K5: fused, scalar-broadcast weights (unchanged, known-correct) ----
__global__ __launch_bounds__(256) void k_fused(const float* __restrict__ xyz,
                                               const float* __restrict__ points,
                                               const float* __restrict__ am,
                                               const float* __restrict__ wf,
                                               const int* __restrict__ gidx,
                                               const float* __restrict__ fpin,
                                               float* __restrict__ out1){
  __shared__ float smem[64*68*2];             // H1 | H2, later overlaid by DNP[64][132]
  __shared__ float Hf1[2][64], Hf2[2][64], F3l[2][128];
  float* H1  = smem;
  float* H2  = smem + 64*68;
  float* DNP = smem;

  int tid  = threadIdx.x;
  int lane = tid & 63;
  int k    = lane & 31;
  int ctr  = lane >> 5;
  int wv   = __builtin_amdgcn_readfirstlane(tid >> 6);   // uniform wave id
  int s0   = blockIdx.x*2;
  int s    = s0 + ctr;
  int b    = s >> 10;
  int si   = s & (SS-1);
  int row  = lane;

  // ---- gather own neighbor row into registers ----
  int ki = gidx[s*KNB + k];
  const float* X = xyz + (size_t)b*3*NN;
  const float* P = points + (size_t)b*6*NN;
  float fin0 = fpin[s*9+0], fin1 = fpin[s*9+1], fin2 = fpin[s*9+2];
  float gx0 = X[ki]      - fin0;
  float gx1 = X[NN+ki]   - fin1;
  float gx2 = X[2*NN+ki] - fin2;
  float g3 = P[ki], g4 = P[NN+ki], g5 = P[2*NN+ki];
  float g6 = P[3*NN+ki], g7 = P[4*NN+ki], g8 = P[5*NN+ki];

  // ---- main L0: 9 -> 64, wave slice f0 = wv*16 ----
  {
    int f0 = wv*16;
    float acc[16];
    #pragma unroll
    for (int j=0;j<16;j++) acc[j] = wf[B0F + f0 + j];
    #pragma unroll
    for (int c=0;c<9;c++){
      float xv = (c==0)?gx0:(c==1)?gx1:(c==2)?gx2:(c==3)?g3:(c==4)?g4:(c==5)?g5:(c==6)?g6:(c==7)?g7:g8;
      const float* wr = wf + W0T + c*64 + f0;
      #pragma unroll
      for (int j=0;j<16;j++) acc[j] = fmaf(xv, wr[j], acc[j]);
    }
    #pragma unroll
    for (int j=0;j<16;j+=4){
      float4 o; o.x=fmaxf(acc[j],0.f); o.y=fmaxf(acc[j+1],0.f);
      o.z=fmaxf(acc[j+2],0.f); o.w=fmaxf(acc[j+3],0.f);
      *(float4*)&H1[row*68 + f0 + j] = o;
    }
  }
  // fps-branch L0 (coalesced per-f weight reads)
  if (tid < 128){
    int f = tid & 63; int cf = tid >> 6;
    int sf = s0 + cf;
    float acc = wf[B0F + f];
    #pragma unroll
    for (int c=0;c<9;c++) acc = fmaf(fpin[sf*9+c], wf[W0T + c*64 + f], acc);
    Hf1[cf][f] = fmaxf(acc, 0.0f);
  }
  __syncthreads();

  // ---- main L1: 64 -> 64 ----
  {
    int f0 = wv*16;
    float acc[16];
    #pragma unroll
    for (int j=0;j<16;j++) acc[j] = wf[B1F + f0 + j];
    #pragma unroll 8
    for (int c4=0;c4<16;c4++){
      float4 hv = *(const float4*)&H1[row*68 + c4*4];
      const float* wr = wf + W1T + c4*4*64 + f0;
      #pragma unroll
      for (int j=0;j<16;j++) acc[j] = fmaf(hv.x, wr[j],     acc[j]);
      #pragma unroll
      for (int j=0;j<16;j++) acc[j] = fmaf(hv.y, wr[64+j],  acc[j]);
      #pragma unroll
      for (int j=0;j<16;j++) acc[j] = fmaf(hv.z, wr[128+j], acc[j]);
      #pragma unroll
      for (int j=0;j<16;j++) acc[j] = fmaf(hv.w, wr[192+j], acc[j]);
    }
    #pragma unroll
    for (int j=0;j<16;j+=4){
      float4 o; o.x=fmaxf(acc[j],0.f); o.y=fmaxf(acc[j+1],0.f);
      o.z=fmaxf(acc[j+2],0.f); o.w=fmaxf(acc[j+3],0.f);
      *(float4*)&H2[row*68 + f0 + j] = o;
    }
  }
  if (tid < 128){
    int f = tid & 63; int cf = tid >> 6;
    float acc = wf[B1F + f];
    #pragma unroll 16
    for (int c=0;c<64;c++) acc = fmaf(Hf1[cf][c], wf[W1T + c*64 + f], acc);
    Hf2[cf][f] = fmaxf(acc, 0.0f);
  }
  __syncthreads();

  // ---- main L2: 64 -> 128, np kept in regs ----
  float np[32];
  {
    int f0 = wv*32;
    #pragma unroll
    for (int j=0;j<32;j++) np[j] = wf[B2F + f0 + j];
    #pragma unroll 4
    for (int c4=0;c4<16;c4++){
      float4 hv = *(const float4*)&H2[row*68 + c4*4];
      const float* wr = wf + W2T + c4*4*128 + f0;
      #pragma unroll
      for (int j=0;j<32;j++) np[j] = fmaf(hv.x, wr[j],     np[j]);
      #pragma unroll
      for (int j=0;j<32;j++) np[j] = fmaf(hv.y, wr[128+j], np[j]);
      #pragma unroll
      for (int j=0;j<32;j++) np[j] = fmaf(hv.z, wr[256+j], np[j]);
      #pragma unroll
      for (int j=0;j<32;j++) np[j] = fmaf(hv.w, wr[384+j], np[j]);
    }
    #pragma unroll
    for (int j=0;j<32;j++) np[j] = fmaxf(np[j], 0.0f);
  }
  // fps-branch L2: all 256 threads, f = tid&127
  {
    int f = tid & 127; int cf = tid >> 7;
    float acc = wf[B2F + f];
    #pragma unroll 16
    for (int c=0;c<64;c++) acc = fmaf(Hf2[cf][c], wf[W2T + c*128 + f], acc);
    F3l[cf][f] = fmaxf(acc, 0.0f);
  }
  __syncthreads();          // all H2 reads done; F3l visible

  // ---- DNP = F3 - np (overlays H1/H2) ----
  {
    int f0 = wv*32;
    #pragma unroll
    for (int j=0;j<32;j+=4){
      float4 d;
      d.x = F3l[ctr][f0+j]   - np[j];
      d.y = F3l[ctr][f0+j+1] - np[j+1];
      d.z = F3l[ctr][f0+j+2] - np[j+2];
      d.w = F3l[ctr][f0+j+3] - np[j+3];
      *(float4*)&DNP[row*132 + f0 + j] = d;
    }
  }
  __syncthreads();

  // ---- attention + softmax + pool ----
  {
    float dp0 = -gx0, dp1 = -gx1, dp2 = -gx2;
    size_t ob = (size_t)b*128*SS + si;
    #pragma unroll
    for (int p=0;p<4;p++){
      int f0 = wv*32 + p*8;
      float e[8];
      const float* a0 = am + f0;
      #pragma unroll
      for (int j=0;j<8;j++)
        e[j] = fmaf(dp2, a0[256+j], fmaf(dp1, a0[128+j], dp0*a0[j]));
      #pragma unroll 4
      for (int c4=0;c4<32;c4++){
        float4 dv = *(const float4*)&DNP[row*132 + c4*4];
        const float* wr = am + (3 + c4*4)*128 + f0;
        #pragma unroll
        for (int j=0;j<8;j++) e[j] = fmaf(dv.x, wr[j],     e[j]);
        #pragma unroll
        for (int j=0;j<8;j++) e[j] = fmaf(dv.y, wr[128+j], e[j]);
        #pragma unroll
        for (int j=0;j<8;j++) e[j] = fmaf(dv.z, wr[256+j], e[j]);
        #pragma unroll
        for (int j=0;j<8;j++) e[j] = fmaf(dv.w, wr[384+j], e[j]);
      }
      #pragma unroll
      for (int j=0;j<8;j++){
        float ej = e[j]; ej = (ej >= 0.0f) ? ej : 0.2f*ej;
        float mx = ej;
        mx = fmaxf(mx, __shfl_xor(mx,1));
        mx = fmaxf(mx, __shfl_xor(mx,2));
        mx = fmaxf(mx, __shfl_xor(mx,4));
        mx = fmaxf(mx, __shfl_xor(mx,8));
        mx = fmaxf(mx, __shfl_xor(mx,16));
        float pp = __expf(ej - mx);
        float sm = pp;
        sm += __shfl_xor(sm,1); sm += __shfl_xor(sm,2); sm += __shfl_xor(sm,4);
        sm += __shfl_xor(sm,8); sm += __shfl_xor(sm,16);
        float po = (pp / sm) * np[p*8+j];
        po += __shfl_xor(po,1); po += __shfl_xor(po,2); po += __shfl_xor(po,4);
        po += __shfl_xor(po,8); po += __shfl_xor(po,16);
        if (k == 0) out1[ob + (size_t)(f0+j)*SS] = po;
      }
    }
  }
}

extern "C" void kernel_launch(void* const* d_in, const int* in_sizes, int n_in,
                              void* d_out, int out_size, void* d_ws, size_t ws_size,
                              hipStream_t stream){
  (void)in_sizes; (void)n_in; (void)out_size; (void)ws_size;
  const float* xyz    = (const float*)d_in[0];
  const float* points = (const float*)d_in[1];
  const float* am     = (const float*)d_in[20];
  float* ws  = (float*)d_ws;
  int*   fpsidx = (int*)d_ws + FPSIDX_OFF;
  int*   gidx   = (int*)d_ws + GIDX_OFF;
  float* nrm    = ws + NORM_OFF;
  float* fpin   = ws + FPIN_OFF;
  float* wf     = ws + WF_OFF;
  float* out0   = (float*)d_out;
  float* out1   = (float*)d_out + BB*3*SS;

  k_fold<<<1,128,0,stream>>>(
      (const float*)d_in[2],(const float*)d_in[3],(const float*)d_in[4],(const float*)d_in[5],(const float*)d_in[6],(const float*)d_in[7],
      (const float*)d_in[8],(const float*)d_in[9],(const float*)d_in[10],(const float*)d_in[11],(const float*)d_in[12],(const float*)d_in[13],
      (const float*)d_in[14],(const float*)d_in[15],(const float*)d_in[16],(const float*)d_in[17],(const float*)d_in[18],(const float*)d_in[19],
      wf);
  k_norm<<<BB*NN/256,256,0,stream>>>(xyz, nrm);
  k_fps<<<BB,512,0,stream>>>(xyz, fpsidx);
  k_ball<<<BB*SS/4,256,0,stream>>>(xyz, points, nrm, fpsidx, gidx, fpin, out0);
  k_fused<<<BB*SS/2,256,0,stream>>>(xyz, points, am, wf, gidx, fpin, out1);
}

// Round 6
// 1137.394 us; speedup vs baseline: 1.0548x; 1.0548x over previous
//
#include <hip/hip_runtime.h>

#define BB 16
#define NN 4096
#define SS 1024
#define KNB 32

// ---- ws layout (in 4-byte words) ----
#define FPSIDX_OFF 0                         // int[BB*SS]
#define GIDX_OFF   (BB*SS)                   // int[BB*SS*KNB]
#define NORM_OFF   (GIDX_OFF + BB*SS*KNB)    // float[BB*NN]
#define FPIN_OFF   (NORM_OFF + BB*NN)        // float[BB*SS*9]
#define WF_OFF     (FPIN_OFF + BB*SS*9)      // float[13120]

// folded-weight layout (floats, within wf)
#define W0T 0          // [9][64]
#define B0F 576
#define W1T 640        // [64][64]
#define B1F 4736
#define W2T 4800       // [64][128]
#define B2F 12992

typedef float v2f __attribute__((ext_vector_type(2)));

// ---- K1: fold BN into weights, transpose to [c][f] ----
__global__ __launch_bounds__(128) void k_fold(
    const float* W0,const float* b0,const float* g0,const float* be0,const float* m0,const float* v0,
    const float* W1,const float* b1,const float* g1,const float* be1,const float* m1,const float* v1,
    const float* W2,const float* b2,const float* g2,const float* be2,const float* m2,const float* v2,
    float* wf){
  int t = threadIdx.x;
  if (t < 64){
    float s = g0[t]/sqrtf(v0[t]+1e-5f);
    wf[B0F+t] = (b0[t]-m0[t])*s + be0[t];
    for (int c=0;c<9;c++) wf[W0T + c*64 + t] = W0[t*9+c]*s;
    float s1 = g1[t]/sqrtf(v1[t]+1e-5f);
    wf[B1F+t] = (b1[t]-m1[t])*s1 + be1[t];
    for (int c=0;c<64;c++) wf[W1T + c*64 + t] = W1[t*64+c]*s1;
  }
  if (t < 128){
    float s2 = g2[t]/sqrtf(v2[t]+1e-5f);
    wf[B2F+t] = (b2[t]-m2[t])*s2 + be2[t];
    for (int c=0;c<64;c++) wf[W2T + c*128 + t] = W2[t*64+c]*s2;
  }
}

// ---- K2: per-point squared norms (exact ref order, no FMA) ----
__global__ __launch_bounds__(256) void k_norm(const float* xyz, float* nrm){
  int i = blockIdx.x*256 + threadIdx.x;     // < BB*NN
  int b = i >> 12, n = i & (NN-1);
  const float* X = xyz + (size_t)b*3*NN;
  float x=X[n], y=X[NN+n], z=X[2*NN+n];
  nrm[i] = __fadd_rn(__fadd_rn(__fmul_rn(x,x),__fmul_rn(y,y)),__fmul_rn(z,z));
}

// ---- K3: farthest point sampling ----
// 256 thr (4 waves, r4-proven skeleton). 16 pts/thread as 8 float2 pairs
// (contract(off): plain ops == __fmul_rn/__fadd_rn, packable to v_pk).
// u64-key DPP wave argmax (r4-proven); lane0/wave writes 1 slot, single
// double-buffered barrier; 3-compare scan; float4 centroid read.
// fps indices buffered in LDS, flushed once at end -> no vmem in loop,
// so the barrier's implicit vmcnt(0) never stalls on a global store.
template<int CTRL, int RMASK>
__device__ __forceinline__ void dpp_max_step(unsigned &lo, unsigned &hi){
  unsigned nlo = (unsigned)__builtin_amdgcn_update_dpp(0, (int)lo, CTRL, RMASK, 0xF, false);
  unsigned nhi = (unsigned)__builtin_amdgcn_update_dpp(0, (int)hi, CTRL, RMASK, 0xF, false);
  unsigned long long cand = ((unsigned long long)nhi<<32) | nlo;
  unsigned long long curk = ((unsigned long long)hi<<32)  | lo;
  if (cand > curk){ lo = nlo; hi = nhi; }
}

__global__ __launch_bounds__(256) void k_fps(const float* xyz, int* fpsidx){
  #pragma clang fp contract(off)
  __shared__ float4 pxyz4[NN];
  __shared__ unsigned long long red[2][4];
  __shared__ int fpsl[SS];
  int b = blockIdx.x, tid = threadIdx.x;
  int w = tid >> 6, lane = tid & 63;
  const float* X = xyz + (size_t)b*3*NN;
  v2f lx[8], ly[8], lz[8], dist[8];
  #pragma unroll
  for (int m=0;m<8;m++){
    int p0 = tid + (2*m)*256, p1 = tid + (2*m+1)*256;
    float x0=X[p0], y0=X[NN+p0], z0=X[2*NN+p0];
    float x1=X[p1], y1=X[NN+p1], z1=X[2*NN+p1];
    float4 q0; q0.x=x0; q0.y=y0; q0.z=z0; q0.w=0.f;
    float4 q1; q1.x=x1; q1.y=y1; q1.z=z1; q1.w=0.f;
    pxyz4[p0] = q0; pxyz4[p1] = q1;
    lx[m].x=x0; lx[m].y=x1; ly[m].x=y0; ly[m].y=y1; lz[m].x=z0; lz[m].y=z1;
    dist[m].x=1e10f; dist[m].y=1e10f;
  }
  if (tid==0) fpsl[0] = 0;
  float cx = X[0], cy = X[NN], cz = X[2*NN];
  __syncthreads();
  for (int t=1;t<SS;t++){
    v2f cxx, cyy, czz;
    cxx.x=cx; cxx.y=cx; cyy.x=cy; cyy.y=cy; czz.x=cz; czz.y=cz;
    float bv = -1.0f; int bj = 0;
    #pragma unroll
    for (int m=0;m<8;m++){
      v2f dx = lx[m]-cxx, dy = ly[m]-cyy, dz = lz[m]-czz;
      v2f dd = (dx*dx + dy*dy) + dz*dz;
      v2f nd; nd.x = fminf(dist[m].x, dd.x); nd.y = fminf(dist[m].y, dd.y);
      dist[m] = nd;
      // pair-internal first-max (strict >: ties keep earlier element)
      bool pc = nd.y > nd.x;
      float vm = pc ? nd.y : nd.x;
      int   jm = pc ? (2*m+1) : (2*m);
      // vs running best (strict >: ties keep earlier pair)
      bool c = vm > bv;
      bv = c ? vm : bv;
      bj = c ? jm : bj;
    }
    int bi = tid + (bj << 8);                 // global point index (stride 256)
    unsigned lo = 0xFFFFFFFFu - (unsigned)bi; // ~idx: smaller idx -> bigger key
    unsigned hi = __float_as_uint(bv);        // dist>=0: bits monotone
    dpp_max_step<0x111,0xF>(lo,hi);   // row_shr:1
    dpp_max_step<0x112,0xF>(lo,hi);   // row_shr:2
    dpp_max_step<0x114,0xF>(lo,hi);   // row_shr:4
    dpp_max_step<0x118,0xF>(lo,hi);   // row_shr:8
    dpp_max_step<0x142,0xA>(lo,hi);   // row_bcast:15 -> rows 1,3
    dpp_max_step<0x143,0xC>(lo,hi);   // row_bcast:31 -> rows 2,3
    unsigned glo = (unsigned)__builtin_amdgcn_readlane((int)lo, 63);
    unsigned ghi = (unsigned)__builtin_amdgcn_readlane((int)hi, 63);
    if (lane==0) red[t&1][w] = ((unsigned long long)ghi<<32) | glo;
    __syncthreads();
    unsigned long long k0 = red[t&1][0], k1 = red[t&1][1];
    unsigned long long k2 = red[t&1][2], k3 = red[t&1][3];
    unsigned long long a0 = (k1>k0)?k1:k0;
    unsigned long long a1 = (k3>k2)?k3:k2;
    unsigned long long bk = (a1>a0)?a1:a0;
    int cur = (int)(0xFFFFFFFFu - (unsigned)(bk & 0xFFFFFFFFull));
    float4 cc = pxyz4[cur];
    cx = cc.x; cy = cc.y; cz = cc.z;
    if (tid==0) fpsl[t] = cur;
  }
  __syncthreads();
  #pragma unroll
  for (int q=0;q<4;q++){
    int i = tid + q*256;
    fpsidx[b*SS + i] = fpsl[i];
  }
}

// ---- K4: ball query (unchanged, known-correct) ----
__global__ __launch_bounds__(256) void k_ball(const float* xyz, const float* points, const float* nrm,
                                              const int* fpsidx, int* gidx, float* fpin, float* out0){
  int wid = threadIdx.x >> 6, lane = threadIdx.x & 63;
  int s = blockIdx.x*4 + wid;
  int b = s >> 10, si = s & (SS-1);
  const float* X = xyz + (size_t)b*3*NN;
  int cidx = fpsidx[s];
  float sx = X[cidx], sy = X[NN+cidx], sz = X[2*NN+cidx];
  float sn = nrm[b*NN + cidx];
  if (lane < 3){
    float v = lane==0?sx:(lane==1?sy:sz);
    fpin[s*9+lane] = v;
    out0[b*3*SS + lane*SS + si] = v;
  } else if (lane < 9){
    fpin[s*9+lane] = points[(size_t)b*6*NN + (size_t)(lane-3)*NN + cidx];
  }
  const float R2 = (float)(0.2*0.2);
  int total = 0; int first = 0;
  for (int ch=0; ch<NN/64; ch++){
    int n = ch*64 + lane;
    float pxv=X[n], pyv=X[NN+n], pzv=X[2*NN+n];
    float dot = __fmaf_rn(sz,pzv, __fmaf_rn(sy,pyv, __fmul_rn(sx,pxv)));
    float sqr = __fadd_rn(__fadd_rn(__fmul_rn(-2.0f,dot), sn), nrm[b*NN+n]);
    bool inc = (sqr <= R2);
    unsigned long long mask = __ballot(inc);
    if (total == 0 && mask != 0ull) first = ch*64 + (__ffsll((long long)mask) - 1);
    if (inc){
      int pos = total + __popcll(mask & ((1ull<<lane)-1ull));
      if (pos < KNB) gidx[s*KNB + pos] = n;
    }
    total += (int)__popcll(mask);
    if (total >= KNB) break;
  }
  if (total < KNB && lane >= total && lane < KNB) gidx[s*KNB + lane] = first;
}

// ---- K5: fused, scalar-broadcast weights (unchanged, known-correct) ----
__global__ __launch_bounds__(256) void k_fused(const float* __restrict__ xyz,
                                               const float* __restrict__ points,
                                               const float* __restrict__ am,
                                               const float* __restrict__ wf,
                                               const int* __restrict__ gidx,
                                               const float* __restrict__ fpin,
                                               float* __restrict__ out1){
  __shared__ float smem[64*68*2];             // H1 | H2, later overlaid by DNP[64][132]
  __shared__ float Hf1[2][64], Hf2[2][64], F3l[2][128];
  float* H1  = smem;
  float* H2  = smem + 64*68;
  float* DNP = smem;

  int tid  = threadIdx.x;
  int lane = tid & 63;
  int k    = lane & 31;
  int ctr  = lane >> 5;
  int wv   = __builtin_amdgcn_readfirstlane(tid >> 6);   // uniform wave id
  int s0   = blockIdx.x*2;
  int s    = s0 + ctr;
  int b    = s >> 10;
  int si   = s & (SS-1);
  int row  = lane;

  // ---- gather own neighbor row into registers ----
  int ki = gidx[s*KNB + k];
  const float* X = xyz + (size_t)b*3*NN;
  const float* P = points + (size_t)b*6*NN;
  float fin0 = fpin[s*9+0], fin1 = fpin[s*9+1], fin2 = fpin[s*9+2];
  float gx0 = X[ki]      - fin0;
  float gx1 = X[NN+ki]   - fin1;
  float gx2 = X[2*NN+ki] - fin2;
  float g3 = P[ki], g4 = P[NN+ki], g5 = P[2*NN+ki];
  float g6 = P[3*NN+ki], g7 = P[4*NN+ki], g8 = P[5*NN+ki];

  // ---- main L0: 9 -> 64, wave slice f0 = wv*16 ----
  {
    int f0 = wv*16;
    float acc[16];
    #pragma unroll
    for (int j=0;j<16;j++) acc[j] = wf[B0F + f0 + j];
    #pragma unroll
    for (int c=0;c<9;c++){
      float xv = (c==0)?gx0:(c==1)?gx1:(c==2)?gx2:(c==3)?g3:(c==4)?g4:(c==5)?g5:(c==6)?g6:(c==7)?g7:g8;
      const float* wr = wf + W0T + c*64 + f0;
      #pragma unroll
      for (int j=0;j<16;j++) acc[j] = fmaf(xv, wr[j], acc[j]);
    }
    #pragma unroll
    for (int j=0;j<16;j+=4){
      float4 o; o.x=fmaxf(acc[j],0.f); o.y=fmaxf(acc[j+1],0.f);
      o.z=fmaxf(acc[j+2],0.f); o.w=fmaxf(acc[j+3],0.f);
      *(float4*)&H1[row*68 + f0 + j] = o;
    }
  }
  // fps-branch L0 (coalesced per-f weight reads)
  if (tid < 128){
    int f = tid & 63; int cf = tid >> 6;
    int sf = s0 + cf;
    float acc = wf[B0F + f];
    #pragma unroll
    for (int c=0;c<9;c++) acc = fmaf(fpin[sf*9+c], wf[W0T + c*64 + f], acc);
    Hf1[cf][f] = fmaxf(acc, 0.0f);
  }
  __syncthreads();

  // ---- main L1: 64 -> 64 ----
  {
    int f0 = wv*16;
    float acc[16];
    #pragma unroll
    for (int j=0;j<16;j++) acc[j] = wf[B1F + f0 + j];
    #pragma unroll 8
    for (int c4=0;c4<16;c4++){
      float4 hv = *(const float4*)&H1[row*68 + c4*4];
      const float* wr = wf + W1T + c4*4*64 + f0;
      #pragma unroll
      for (int j=0;j<16;j++) acc[j] = fmaf(hv.x, wr[j],     acc[j]);
      #pragma unroll
      for (int j=0;j<16;j++) acc[j] = fmaf(hv.y, wr[64+j],  acc[j]);
      #pragma unroll
      for (int j=0;j<16;j++) acc[j] = fmaf(hv.z, wr[128+j], acc[j]);
      #pragma unroll
      for (int j=0;j<16;j++) acc[j] = fmaf(hv.w, wr[192+j], acc[j]);
    }
    #pragma unroll
    for (int j=0;j<16;j+=4){
      float4 o; o.x=fmaxf(acc[j],0.f); o.y=fmaxf(acc[j+1],0.f);
      o.z=fmaxf(acc[j+2],0.f); o.w=fmaxf(acc[j+3],0.f);
      *(float4*)&H2[row*68 + f0 + j] = o;
    }
  }
  if (tid < 128){
    int f = tid & 63; int cf = tid >> 6;
    float acc = wf[B1F + f];
    #pragma unroll 16
    for (int c=0;c<64;c++) acc = fmaf(Hf1[cf][c], wf[W1T + c*64 + f], acc);
    Hf2[cf][f] = fmaxf(acc, 0.0f);
  }
  __syncthreads();

  // ---- main L2: 64 -> 128, np kept in regs ----
  float np[32];
  {
    int f0 = wv*32;
    #pragma unroll
    for (int j=0;j<32;j++) np[j] = wf[B2F + f0 + j];
    #pragma unroll 4
    for (int c4=0;c4<16;c4++){
      float4 hv = *(const float4*)&H2[row*68 + c4*4];
      const float* wr = wf + W2T + c4*4*128 + f0;
      #pragma unroll
      for (int j=0;j<32;j++) np[j] = fmaf(hv.x, wr[j],     np[j]);
      #pragma unroll
      for (int j=0;j<32;j++) np[j] = fmaf(hv.y, wr[128+j], np[j]);
      #pragma unroll
      for (int j=0;j<32;j++) np[j] = fmaf(hv.z, wr[256+j], np[j]);
      #pragma unroll
      for (int j=0;j<32;j++) np[j] = fmaf(hv.w, wr[384+j], np[j]);
    }
    #pragma unroll
    for (int j=0;j<32;j++) np[j] = fmaxf(np[j], 0.0f);
  }
  // fps-branch L2: all 256 threads, f = tid&127
  {
    int f = tid & 127; int cf = tid >> 7;
    float acc = wf[B2F + f];
    #pragma unroll 16
    for (int c=0;c<64;c++) acc = fmaf(Hf2[cf][c], wf[W2T + c*128 + f], acc);
    F3l[cf][f] = fmaxf(acc, 0.0f);
  }
  __syncthreads();          // all H2 reads done; F3l visible

  // ---- DNP = F3 - np (overlays H1/H2) ----
  {
    int f0 = wv*32;
    #pragma unroll
    for (int j=0;j<32;j+=4){
      float4 d;
      d.x = F3l[ctr][f0+j]   - np[j];
      d.y = F3l[ctr][f0+j+1] - np[j+1];
      d.z = F3l[ctr][f0+j+2] - np[j+2];
      d.w = F3l[ctr][f0+j+3] - np[j+3];
      *(float4*)&DNP[row*132 + f0 + j] = d;
    }
  }
  __syncthreads();

  // ---- attention + softmax + pool ----
  {
    float dp0 = -gx0, dp1 = -gx1, dp2 = -gx2;
    size_t ob = (size_t)b*128*SS + si;
    #pragma unroll
    for (int p=0;p<4;p++){
      int f0 = wv*32 + p*8;
      float e[8];
      const float* a0 = am + f0;
      #pragma unroll
      for (int j=0;j<8;j++)
        e[j] = fmaf(dp2, a0[256+j], fmaf(dp1, a0[128+j], dp0*a0[j]));
      #pragma unroll 4
      for (int c4=0;c4<32;c4++){
        float4 dv = *(const float4*)&DNP[row*132 + c4*4];
        const float* wr = am + (3 + c4*4)*128 + f0;
        #pragma unroll
        for (int j=0;j<8;j++) e[j] = fmaf(dv.x, wr[j],     e[j]);
        #pragma unroll
        for (int j=0;j<8;j++) e[j] = fmaf(dv.y, wr[128+j], e[j]);
        #pragma unroll
        for (int j=0;j<8;j++) e[j] = fmaf(dv.z, wr[256+j], e[j]);
        #pragma unroll
        for (int j=0;j<8;j++) e[j] = fmaf(dv.w, wr[384+j], e[j]);
      }
      #pragma unroll
      for (int j=0;j<8;j++){
        float ej = e[j]; ej = (ej >= 0.0f) ? ej : 0.2f*ej;
        float mx = ej;
        mx = fmaxf(mx, __shfl_xor(mx,1));
        mx = fmaxf(mx, __shfl_xor(mx,2));
        mx = fmaxf(mx, __shfl_xor(mx,4));
        mx = fmaxf(mx, __shfl_xor(mx,8));
        mx = fmaxf(mx, __shfl_xor(mx,16));
        float pp = __expf(ej - mx);
        float sm = pp;
        sm += __shfl_xor(sm,1); sm += __shfl_xor(sm,2); sm += __shfl_xor(sm,4);
        sm += __shfl_xor(sm,8); sm += __shfl_xor(sm,16);
        float po = (pp / sm) * np[p*8+j];
        po += __shfl_xor(po,1); po += __shfl_xor(po,2); po += __shfl_xor(po,4);
        po += __shfl_xor(po,8); po += __shfl_xor(po,16);
        if (k == 0) out1[ob + (size_t)(f0+j)*SS] = po;
      }
    }
  }
}

extern "C" void kernel_launch(void* const* d_in, const int* in_sizes, int n_in,
                              void* d_out, int out_size, void* d_ws, size_t ws_size,
                              hipStream_t stream){
  (void)in_sizes; (void)n_in; (void)out_size; (void)ws_size;
  const float* xyz    = (const float*)d_in[0];
  const float* points = (const float*)d_in[1];
  const float* am     = (const float*)d_in[20];
  float* ws  = (float*)d_ws;
  int*   fpsidx = (int*)d_ws + FPSIDX_OFF;
  int*   gidx   = (int*)d_ws + GIDX_OFF;
  float* nrm    = ws + NORM_OFF;
  float* fpin   = ws + FPIN_OFF;
  float* wf     = ws + WF_OFF;
  float* out0   = (float*)d_out;
  float* out1   = (float*)d_out + BB*3*SS;

  k_fold<<<1,128,0,stream>>>(
      (const float*)d_in[2],(const float*)d_in[3],(const float*)d_in[4],(const float*)d_in[5],(const float*)d_in[6],(const float*)d_in[7],
      (const float*)d_in[8],(const float*)d_in[9],(const float*)d_in[10],(const float*)d_in[11],(const float*)d_in[12],(const float*)d_in[13],
      (const float*)d_in[14],(const float*)d_in[15],(const float*)d_in[16],(const float*)d_in[17],(const float*)d_in[18],(const float*)d_in[19],
      wf);
  k_norm<<<BB*NN/256,256,0,stream>>>(xyz, nrm);
  k_fps<<<BB,256,0,stream>>>(xyz, fpsidx);
  k_ball<<<BB*SS/4,256,0,stream>>>(xyz, points, nrm, fpsidx, gidx, fpin, out0);
  k_fused<<<BB*SS/2,256,0,stream>>>(xyz, points, am, wf, gidx, fpin, out1);
}